// Round 7
// baseline (889.796 us; speedup 1.0000x reference)
//
#include <hip/hip_runtime.h>
#include <hip/hip_bf16.h>

#define NROWS 131072
#define KC 1024
#define DD 128
#define MARGIN 1e-3f

typedef __attribute__((ext_vector_type(8))) short short8;
typedef __attribute__((ext_vector_type(4))) float f32x4;
typedef __attribute__((ext_vector_type(2))) float f32x2;

__device__ inline short f2bf_hi(float f) {
  unsigned u = __builtin_bit_cast(unsigned, f);
  u += 0x7fffu + ((u >> 16) & 1u);   // round-to-nearest-even
  return (short)(u >> 16);
}
__device__ inline float bf2f(short s) {
  unsigned u = ((unsigned)(unsigned short)s) << 16;
  return __builtin_bit_cast(float, u);
}

// Prep: embedding -> fragment-ordered bf16 hi/lo + exact row norms; zero loss slot.
// Fragment order: idx = ((c*4 + s)*64 + l), lane l = q*16+n holds e[16c+n][32s+8q+j], j=0..7
__global__ void vq_prep(const float* __restrict__ E, short* __restrict__ EH,
                        short* __restrict__ EL, float* __restrict__ SE,
                        float* __restrict__ out) {
  int b = blockIdx.x, t = threadIdx.x;
  if (b < 64) {
    int idx = b * 256 + t;
    int s = (idx >> 6) & 3, l = idx & 63;
    int c = idx >> 8;
    int q = l >> 4, n = l & 15;
    const float* src = E + (16 * c + n) * DD + 32 * s + 8 * q;
    short8 h, lo;
#pragma unroll
    for (int j = 0; j < 8; ++j) {
      float x = src[j];
      short hb = f2bf_hi(x);
      h[j] = hb;
      lo[j] = f2bf_hi(x - bf2f(hb));
    }
    *(short8*)(EH + idx * 8) = h;
    *(short8*)(EL + idx * 8) = lo;
  } else {
    if (t == 0) out[0] = 0.f;
    for (int k = t; k < KC; k += 256) {
      double acc = 0.0;
      const float* er = E + k * DD;
      for (int i = 0; i < DD; ++i) { double v = (double)er[i]; acc += v * v; }
      SE[k] = (float)acc;
    }
  }
}

// R7 SPLIT: argmin-only kernel. 3-pass hi/lo bf16 MFMA over 16 rotated chunks,
// top-2 + exact fp64 repair; writes one index per row to IDX (workspace).
// No output streaming here -> chunk loop is pure {L2 stage + MFMA + fold}.
// Invariants kept: LDS staging (R3: direct-global loses L2, FETCH 90->620MB),
// full __syncthreads per chunk (R4: lgkm-only barriers thrashed L2).
__global__ __launch_bounds__(256, 4) void vq_argmin(
    const float* __restrict__ X, const float* __restrict__ E,
    const short* __restrict__ EH, const short* __restrict__ EL,
    const float* __restrict__ SE, int* __restrict__ IDX) {
  __shared__ __align__(16) short lbh[8192];   // 16 KB: B-hi chunk
  __shared__ __align__(16) short lbl[8192];   // 16 KB: B-lo chunk
  __shared__ __align__(16) float lse[KC];     // 4 KB: |e|^2
  __shared__ int lidx[128];
  __shared__ int lflag[128];
  __shared__ int lany;
  __shared__ float lx[128];
  __shared__ float lrv[4];
  __shared__ int lri[4];
  __shared__ float lsx;

  const int tid = threadIdx.x;
  const int w = tid >> 6, l = tid & 63, q = l >> 4, n = l & 15;
  const int row_base = blockIdx.x * 128;
  const int rot = blockIdx.x & 15;            // decorrelate chunk traffic across blocks
  if (tid == 0) lany = 0;
  *(f32x4*)(lse + tid * 4) = *(const f32x4*)(SE + tid * 4);   // 256 thr x 16 B = 4 KB

  // ---- A fragments: wave w owns rows row_base+32w .. +32 (2 tiles of 16) ----
  short8 ah[2][4], al[2][4];
#pragma unroll
  for (int mt = 0; mt < 2; ++mt) {
    const float* xp = X + (row_base + 32 * w + 16 * mt + n) * DD + 8 * q;
#pragma unroll
    for (int s = 0; s < 4; ++s) {
      f32x4 x0 = *(const f32x4*)(xp + 32 * s);
      f32x4 x1 = *(const f32x4*)(xp + 32 * s + 4);
#pragma unroll
      for (int j = 0; j < 4; ++j) {
        short hb = f2bf_hi(x0[j]);
        ah[mt][s][j] = hb;
        al[mt][s][j] = f2bf_hi(x0[j] - bf2f(hb));
        short hb2 = f2bf_hi(x1[j]);
        ah[mt][s][j + 4] = hb2;
        al[mt][s][j + 4] = f2bf_hi(x1[j] - bf2f(hb2));
      }
    }
  }

  // per-lane running top-2 (score = dot - |e|^2/2, maximize) per row-slot (mt,reg)
  float bestv[8], secv[8];
  int besti[8];
#pragma unroll
  for (int i = 0; i < 8; ++i) { bestv[i] = -3e38f; secv[i] = -3e38f; besti[i] = 0; }

  for (int cc = 0; cc < 16; ++cc) {
    const int ccr = (cc + rot) & 15;
    {  // stage B chunk (16 KB hi + 16 KB lo) into LDS
      const short8* gh = (const short8*)(EH + ccr * 8192);
      const short8* gl = (const short8*)(EL + ccr * 8192);
      short8* dh = (short8*)lbh;
      short8* dl = (short8*)lbl;
#pragma unroll
      for (int i = 0; i < 4; ++i) {
        int u = i * 256 + tid;
        dh[u] = gh[u];
        dl[u] = gl[u];
      }
    }
    __syncthreads();

#pragma unroll
    for (int nt = 0; nt < 4; ++nt) {
      f32x4 a0 = {0.f, 0.f, 0.f, 0.f}, a1 = {0.f, 0.f, 0.f, 0.f};
#pragma unroll
      for (int s = 0; s < 4; ++s) {
        short8 bh  = *(const short8*)(lbh + ((nt * 4 + s) * 64 + l) * 8);
        short8 blo = *(const short8*)(lbl + ((nt * 4 + s) * 64 + l) * 8);
        a0 = __builtin_amdgcn_mfma_f32_16x16x32_bf16(ah[0][s], bh,  a0, 0, 0, 0);
        a1 = __builtin_amdgcn_mfma_f32_16x16x32_bf16(ah[1][s], bh,  a1, 0, 0, 0);
        a0 = __builtin_amdgcn_mfma_f32_16x16x32_bf16(al[0][s], bh,  a0, 0, 0, 0);
        a1 = __builtin_amdgcn_mfma_f32_16x16x32_bf16(al[1][s], bh,  a1, 0, 0, 0);
        a0 = __builtin_amdgcn_mfma_f32_16x16x32_bf16(ah[0][s], blo, a0, 0, 0, 0);
        a1 = __builtin_amdgcn_mfma_f32_16x16x32_bf16(ah[1][s], blo, a1, 0, 0, 0);
      }
      // fold this nt immediately (C layout: col = lane&15, row = quad*4+reg)
      int k = ccr * 64 + nt * 16 + n;
      float hse = 0.5f * lse[k];
#pragma unroll
      for (int r = 0; r < 4; ++r) {
        {
          float sc = a0[r] - hse;
          bool gt = sc > bestv[r];
          secv[r] = gt ? bestv[r] : fmaxf(secv[r], sc);
          if (gt) { bestv[r] = sc; besti[r] = k; }
        }
        {
          int sl = 4 + r;
          float sc = a1[r] - hse;
          bool gt = sc > bestv[sl];
          secv[sl] = gt ? bestv[sl] : fmaxf(secv[sl], sc);
          if (gt) { bestv[sl] = sc; besti[sl] = k; }
        }
      }
    }
    __syncthreads();  // LDS reuse next chunk
  }

  // cross-lane top-2 merge over the 16 column-lanes of each quad (disjoint k-sets)
#pragma unroll
  for (int slot = 0; slot < 8; ++slot) {
    float v = bestv[slot], s2 = secv[slot];
    int bi = besti[slot];
#pragma unroll
    for (int m = 1; m <= 8; m <<= 1) {
      float v2 = __shfl_xor(v, m, 64);
      float sv2 = __shfl_xor(s2, m, 64);
      int i2 = __shfl_xor(bi, m, 64);
      float ns = fmaxf(fminf(v, v2), fmaxf(s2, sv2));
      if (v2 > v || (v2 == v && i2 < bi)) { v = v2; bi = i2; }
      s2 = ns;
    }
    if (n == 0) {
      int mt = slot >> 2, r = slot & 3;
      int rl = 32 * w + 16 * mt + 4 * q + r;
      int f = (v - s2) <= MARGIN;
      lidx[rl] = bi;
      lflag[rl] = f;
      if (f) lany = 1;
    }
  }
  __syncthreads();

  // ---- repair flagged rows: exact fp64 dots, numpy-rounding-emulated distances ----
  if (lany) {
    for (int rl = 0; rl < 128; ++rl) {
      if (lflag[rl] == 0) continue;           // uniform branch (LDS value)
      if (tid < DD) lx[tid] = X[(row_base + rl) * DD + tid];
      __syncthreads();
      if (tid < 64) {                         // sx: row-constant -> argmin-invariant
        double v0 = lx[tid], v1 = lx[tid + 64];
        double s = v0 * v0 + v1 * v1;
#pragma unroll
        for (int m = 1; m < 64; m <<= 1) s += __shfl_xor(s, m, 64);
        if (tid == 0) lsx = (float)s;
      }
      __syncthreads();
      float dmin = 3e38f; int kmin = 0;
      for (int kk = tid; kk < KC; kk += 256) {
        double dot = 0.0;
        const float* er = E + kk * DD;
        for (int i = 0; i < DD; ++i) dot += (double)lx[i] * (double)er[i];
        float a = lsx + lse[kk];
        float b2 = (float)(2.0 * dot);
        float dnp = a - b2;                   // RN(RN(sx+se) - RN(2 dot)) like np
        if (dnp < dmin) { dmin = dnp; kmin = kk; }
      }
#pragma unroll
      for (int m = 1; m < 64; m <<= 1) {      // wave argmin (smaller-index tiebreak)
        float v2 = __shfl_xor(dmin, m, 64);
        int k2 = __shfl_xor(kmin, m, 64);
        if (v2 < dmin || (v2 == dmin && k2 < kmin)) { dmin = v2; kmin = k2; }
      }
      if (l == 0) { lrv[w] = dmin; lri[w] = kmin; }
      __syncthreads();
      if (tid == 0) {
        float dm = lrv[0]; int km = lri[0];
#pragma unroll
        for (int t2 = 1; t2 < 4; ++t2)
          if (lrv[t2] < dm || (lrv[t2] == dm && lri[t2] < km)) { dm = lrv[t2]; km = lri[t2]; }
        lidx[rl] = km;
      }
      __syncthreads();
    }
  }
  __syncthreads();

  if (tid < 128) IDX[row_base + tid] = lidx[tid];   // coalesced index writeout
}

// R7 SPLIT: output-streaming kernel. Pure duplex streaming: st (67MB w + 134MB r)
// then one-hot zeros (537MB NT w, lane-coalesced per R1), barrier (drains NT
// queue -> ordering, R6-verified), then the single 1.0/row + loss.
__global__ __launch_bounds__(256) void vq_out(
    const float* __restrict__ X, const float* __restrict__ E,
    const int* __restrict__ IDX, float* __restrict__ out) {
  __shared__ int lidx[128];
  __shared__ float lloss[4];
  const int tid = threadIdx.x;
  const int w = tid >> 6, l = tid & 63;
  const int row_base = blockIdx.x * 128;
  const int encb = 1 + NROWS * DD;

  if (tid < 128) lidx[tid] = IDX[row_base + tid];
  __syncthreads();

  // ---- quantized_st + loss partials (loads overlap the NT store queue) ----
  float lp = 0.f;
  for (int rl = w; rl < 128; rl += 4) {
    int row = row_base + rl;
    int idx = lidx[rl];
    f32x2 xv = *(const f32x2*)(X + row * DD + 2 * l);
    f32x2 ev = *(const f32x2*)(E + idx * DD + 2 * l);
    float d0 = ev[0] - xv[0], d1 = ev[1] - xv[1];
    __builtin_nontemporal_store(xv[0] + d0, out + 1 + row * DD + 2 * l);
    __builtin_nontemporal_store(xv[1] + d1, out + 1 + row * DD + 2 * l + 1);
    lp += d0 * d0 + d1 * d1;
  }

  // ---- one-hot zeros: block's contiguous 512 KB region, lane-coalesced ----
  float* zb = out + encb + row_base * KC;     // 131072 floats; zb mod 4 == 1
  if (tid < 3) __builtin_nontemporal_store(0.f, zb + tid);          // head
  else if (tid == 3) __builtin_nontemporal_store(0.f, zb + 131071); // tail
  float* zb4 = zb + 3;                        // 16B-aligned; f32x4 j=0..32766
  const f32x4 z4 = {0.f, 0.f, 0.f, 0.f};
  for (int u = 0; u < 127; ++u)
    __builtin_nontemporal_store(z4, (f32x4*)(zb4 + 4 * (u * 256 + tid)));
  if (tid < 255)
    __builtin_nontemporal_store(z4, (f32x4*)(zb4 + 4 * (127 * 256 + tid)));
  __syncthreads();   // vmcnt(0): zeros drained before same-line 1.0 stores

  // ---- the single 1.0 per row ----
  for (int rl = w; rl < 128; rl += 4) {
    int row = row_base + rl;
    int idx = lidx[rl];
    if (l == (idx & 63)) out[encb + row * KC + idx] = 1.f;
  }

  // ---- loss ----
#pragma unroll
  for (int m = 1; m < 64; m <<= 1) lp += __shfl_xor(lp, m, 64);
  if (l == 0) lloss[w] = lp;
  __syncthreads();
  if (tid == 0) {
    float t = (lloss[0] + lloss[1] + lloss[2] + lloss[3]) *
              (1.25f / ((float)NROWS * (float)DD));
    atomicAdd(out, t);   // loss = q_latent + 0.25*e_latent = 1.25*mean
  }
}

extern "C" void kernel_launch(void* const* d_in, const int* in_sizes, int n_in,
                              void* d_out, int out_size, void* d_ws, size_t ws_size,
                              hipStream_t stream) {
  const float* X = (const float*)d_in[0];        // c_input [131072,128] fp32
  const float* E = (const float*)d_in[1];        // embedding [1024,128] fp32
  float* out = (float*)d_out;                    // [loss | quantized_st | encodings]
  short* EH = (short*)d_ws;                      // 256 KB bf16-hi fragments
  short* EL = EH + KC * DD;                      // 256 KB bf16-lo fragments
  float* SE = (float*)(EL + KC * DD);            // 4 KB row norms
  int* IDX = (int*)(SE + KC);                    // 512 KB per-row argmin indices
  vq_prep<<<65, 256, 0, stream>>>(E, EH, EL, SE, out);
  vq_argmin<<<NROWS / 128, 256, 0, stream>>>(X, E, EH, EL, SE, IDX);
  vq_out<<<NROWS / 128, 256, 0, stream>>>(X, E, IDX, out);
}

// Round 9
// 763.070 us; speedup vs baseline: 1.1661x; 1.1661x over previous
//
#include <hip/hip_runtime.h>
#include <hip/hip_bf16.h>

#define NROWS 131072
#define KC 1024
#define DD 128
#define MARGIN 1e-3f

typedef __attribute__((ext_vector_type(8))) short short8;
typedef __attribute__((ext_vector_type(4))) float f32x4;
typedef __attribute__((ext_vector_type(2))) float f32x2;

__device__ inline short f2bf_hi(float f) {
  unsigned u = __builtin_bit_cast(unsigned, f);
  u += 0x7fffu + ((u >> 16) & 1u);   // round-to-nearest-even
  return (short)(u >> 16);
}
__device__ inline float bf2f(short s) {
  unsigned u = ((unsigned)(unsigned short)s) << 16;
  return __builtin_bit_cast(float, u);
}

// Prep: embedding -> fragment-ordered bf16 hi/lo + exact row norms; zero loss slot.
// Fragment order: idx = ((c*4 + s)*64 + l), lane l = q*16+n holds e[16c+n][32s+8q+j], j=0..7
__global__ void vq_prep(const float* __restrict__ E, short* __restrict__ EH,
                        short* __restrict__ EL, float* __restrict__ SE,
                        float* __restrict__ out) {
  int b = blockIdx.x, t = threadIdx.x;
  if (b < 64) {
    int idx = b * 256 + t;
    int s = (idx >> 6) & 3, l = idx & 63;
    int c = idx >> 8;
    int q = l >> 4, n = l & 15;
    const float* src = E + (16 * c + n) * DD + 32 * s + 8 * q;
    short8 h, lo;
#pragma unroll
    for (int j = 0; j < 8; ++j) {
      float x = src[j];
      short hb = f2bf_hi(x);
      h[j] = hb;
      lo[j] = f2bf_hi(x - bf2f(hb));
    }
    *(short8*)(EH + idx * 8) = h;
    *(short8*)(EL + idx * 8) = lo;
  } else {
    if (t == 0) out[0] = 0.f;
    for (int k = t; k < KC; k += 256) {
      double acc = 0.0;
      const float* er = E + k * DD;
      for (int i = 0; i < DD; ++i) { double v = (double)er[i]; acc += v * v; }
      SE[k] = (float)acc;
    }
  }
}

// Fused: 3-pass hi/lo bf16 MFMA argmin over 16 rotated chunks of 64 codes,
// top-2 + exact fp64 repair, then in-kernel outputs (zeros streamed in-loop).
// ARCHITECTURE NOTES (hard-won):
//  - R1: streamed zero stores must be lane-coalesced (tid-consecutive f32x4);
//    scattered 16B/lane = 3x HBM write amplification.
//  - R3: B fragments direct-from-global lose L2 residency under the NT write
//    stream (FETCH 90->620 MB). LDS staging is mandatory.
//  - R4: removing the per-chunk vmcnt(0) drains (lgkm-only barriers) lets the
//    NT store queue run deep and flushes the 512KB codebook out of L2
//    (FETCH 752 MB, +100us). Full __syncthreads at chunk boundaries is LOAD-
//    BEARING: it bounds the store queue and keeps staging L2-hot.
//  - R7: split argmin/out kernels = +105us (fusion hides the write stream).
//  - R8: __launch_bounds__(256,2). At (256,4) the unified VGPR+AGPR cap is 128/
//    wave; live set is ~140-170 (64 A-fragments in AGPR + 8 acc + 24 top-2 state
//    + staging/addr) -> top-2 state spilled to scratch and round-tripped EVERY
//    chunk fold = the persistent ~19us/chunk stall (VGPR_Count=64 every round).
//    (256,2) -> 256 regs/wave, everything resident; 2 blocks/CU is enough for a
//    BW-bound write stream.
__global__ __launch_bounds__(256, 2) void vq_main(
    const float* __restrict__ X, const float* __restrict__ E,
    const short* __restrict__ EH, const short* __restrict__ EL,
    const float* __restrict__ SE, float* __restrict__ out) {
  __shared__ __align__(16) short lbh[8192];   // 16 KB: B-hi chunk
  __shared__ __align__(16) short lbl[8192];   // 16 KB: B-lo chunk
  __shared__ __align__(16) float lse[KC];     // 4 KB: |e|^2
  __shared__ int lidx[128];
  __shared__ int lflag[128];
  __shared__ int lany;
  __shared__ float lx[128];
  __shared__ float lrv[4];
  __shared__ int lri[4];
  __shared__ float lsx;
  __shared__ float lloss[4];

  const int tid = threadIdx.x;
  const int w = tid >> 6, l = tid & 63, q = l >> 4, n = l & 15;
  const int row_base = blockIdx.x * 128;
  const int rot = blockIdx.x & 15;            // decorrelate chunk traffic across blocks
  const int encb = 1 + NROWS * DD;
  if (tid == 0) lany = 0;
  *(f32x4*)(lse + tid * 4) = *(const f32x4*)(SE + tid * 4);   // 256 thr x 16 B = 4 KB

  // one-hot region for this block: floats [0,131072) at zb; zb mod 4 floats == 1
  float* zb = out + encb + row_base * KC;
  if (tid < 3) __builtin_nontemporal_store(0.f, zb + tid);          // head (unaligned)
  else if (tid == 3) __builtin_nontemporal_store(0.f, zb + 131071); // tail
  float* zb4 = zb + 3;                        // 16B-aligned; 32767 f32x4 to zero

  // ---- A fragments: wave w owns rows row_base+32w .. +32 (2 tiles of 16) ----
  short8 ah[2][4], al[2][4];
#pragma unroll
  for (int mt = 0; mt < 2; ++mt) {
    const float* xp = X + (row_base + 32 * w + 16 * mt + n) * DD + 8 * q;
#pragma unroll
    for (int s = 0; s < 4; ++s) {
      f32x4 x0 = *(const f32x4*)(xp + 32 * s);
      f32x4 x1 = *(const f32x4*)(xp + 32 * s + 4);
#pragma unroll
      for (int j = 0; j < 4; ++j) {
        short hb = f2bf_hi(x0[j]);
        ah[mt][s][j] = hb;
        al[mt][s][j] = f2bf_hi(x0[j] - bf2f(hb));
        short hb2 = f2bf_hi(x1[j]);
        ah[mt][s][j + 4] = hb2;
        al[mt][s][j + 4] = f2bf_hi(x1[j] - bf2f(hb2));
      }
    }
  }

  // per-lane running top-2 (score = dot - |e|^2/2, maximize) per row-slot (mt,reg)
  float bestv[8], secv[8];
  int besti[8];
#pragma unroll
  for (int i = 0; i < 8; ++i) { bestv[i] = -3e38f; secv[i] = -3e38f; besti[i] = 0; }

  const f32x4 z4 = {0.f, 0.f, 0.f, 0.f};
  for (int cc = 0; cc < 16; ++cc) {
    const int ccr = (cc + rot) & 15;
    {  // stage B chunk (16 KB hi + 16 KB lo) into LDS
      const short8* gh = (const short8*)(EH + ccr * 8192);
      const short8* gl = (const short8*)(EL + ccr * 8192);
      short8* dh = (short8*)lbh;
      short8* dl = (short8*)lbl;
#pragma unroll
      for (int i = 0; i < 4; ++i) {
        int u = i * 256 + tid;
        dh[u] = gh[u];
        dl[u] = gl[u];
      }
    }
    __syncthreads();

    // issue this chunk's zero stores up front — the MFMA+fold phase below
    // drains them before the closing barrier's vmcnt(0).
    // Lane-coalesced: consecutive tid -> consecutive f32x4 (R1 lesson).
#pragma unroll
    for (int u2 = 0; u2 < 8; ++u2) {
      int j = cc * 2048 + u2 * 256 + tid;
      if (j < 32767) __builtin_nontemporal_store(z4, (f32x4*)(zb4 + 4 * j));
    }
    __builtin_amdgcn_sched_barrier(0);   // pin issue point (don't sink into MFMAs)

#pragma unroll
    for (int nt = 0; nt < 4; ++nt) {
      f32x4 a0 = {0.f, 0.f, 0.f, 0.f}, a1 = {0.f, 0.f, 0.f, 0.f};
#pragma unroll
      for (int s = 0; s < 4; ++s) {
        short8 bh  = *(const short8*)(lbh + ((nt * 4 + s) * 64 + l) * 8);
        short8 blo = *(const short8*)(lbl + ((nt * 4 + s) * 64 + l) * 8);
        a0 = __builtin_amdgcn_mfma_f32_16x16x32_bf16(ah[0][s], bh,  a0, 0, 0, 0);
        a1 = __builtin_amdgcn_mfma_f32_16x16x32_bf16(ah[1][s], bh,  a1, 0, 0, 0);
        a0 = __builtin_amdgcn_mfma_f32_16x16x32_bf16(al[0][s], bh,  a0, 0, 0, 0);
        a1 = __builtin_amdgcn_mfma_f32_16x16x32_bf16(al[1][s], bh,  a1, 0, 0, 0);
        a0 = __builtin_amdgcn_mfma_f32_16x16x32_bf16(ah[0][s], blo, a0, 0, 0, 0);
        a1 = __builtin_amdgcn_mfma_f32_16x16x32_bf16(ah[1][s], blo, a1, 0, 0, 0);
      }
      // fold this nt immediately (C layout: col = lane&15, row = quad*4+reg)
      int k = ccr * 64 + nt * 16 + n;
      float hse = 0.5f * lse[k];
#pragma unroll
      for (int r = 0; r < 4; ++r) {
        {
          float sc = a0[r] - hse;
          bool gt = sc > bestv[r];
          secv[r] = gt ? bestv[r] : fmaxf(secv[r], sc);
          if (gt) { bestv[r] = sc; besti[r] = k; }
        }
        {
          int sl = 4 + r;
          float sc = a1[r] - hse;
          bool gt = sc > bestv[sl];
          secv[sl] = gt ? bestv[sl] : fmaxf(secv[sl], sc);
          if (gt) { bestv[sl] = sc; besti[sl] = k; }
        }
      }
    }
    __syncthreads();  // LDS reuse next chunk; also bounds the NT store queue (R4 lesson)
  }

  // cross-lane top-2 merge over the 16 column-lanes of each quad (disjoint k-sets)
#pragma unroll
  for (int slot = 0; slot < 8; ++slot) {
    float v = bestv[slot], s2 = secv[slot];
    int bi = besti[slot];
#pragma unroll
    for (int m = 1; m <= 8; m <<= 1) {
      float v2 = __shfl_xor(v, m, 64);
      float sv2 = __shfl_xor(s2, m, 64);
      int i2 = __shfl_xor(bi, m, 64);
      float ns = fmaxf(fminf(v, v2), fmaxf(s2, sv2));
      if (v2 > v || (v2 == v && i2 < bi)) { v = v2; bi = i2; }
      s2 = ns;
    }
    if (n == 0) {
      int mt = slot >> 2, r = slot & 3;
      int rl = 32 * w + 16 * mt + 4 * q + r;
      int f = (v - s2) <= MARGIN;
      lidx[rl] = bi;
      lflag[rl] = f;
      if (f) lany = 1;
    }
  }
  __syncthreads();

  // ---- repair flagged rows: exact fp64 dots, numpy-rounding-emulated distances ----
  if (lany) {
    for (int rl = 0; rl < 128; ++rl) {
      if (lflag[rl] == 0) continue;           // uniform branch (LDS value)
      if (tid < DD) lx[tid] = X[(row_base + rl) * DD + tid];
      __syncthreads();
      if (tid < 64) {                         // sx: row-constant -> argmin-invariant
        double v0 = lx[tid], v1 = lx[tid + 64];
        double s = v0 * v0 + v1 * v1;
#pragma unroll
        for (int m = 1; m < 64; m <<= 1) s += __shfl_xor(s, m, 64);
        if (tid == 0) lsx = (float)s;
      }
      __syncthreads();
      float dmin = 3e38f; int kmin = 0;
      for (int kk = tid; kk < KC; kk += 256) {
        double dot = 0.0;
        const float* er = E + kk * DD;
        for (int i = 0; i < DD; ++i) dot += (double)lx[i] * (double)er[i];
        float a = lsx + lse[kk];
        float b2 = (float)(2.0 * dot);
        float dnp = a - b2;                   // RN(RN(sx+se) - RN(2 dot)) like np
        if (dnp < dmin) { dmin = dnp; kmin = kk; }
      }
#pragma unroll
      for (int m = 1; m < 64; m <<= 1) {      // wave argmin (smaller-index tiebreak)
        float v2 = __shfl_xor(dmin, m, 64);
        int k2 = __shfl_xor(kmin, m, 64);
        if (v2 < dmin || (v2 == dmin && k2 < kmin)) { dmin = v2; kmin = k2; }
      }
      if (l == 0) { lrv[w] = dmin; lri[w] = kmin; }
      __syncthreads();
      if (tid == 0) {
        float dm = lrv[0]; int km = lri[0];
#pragma unroll
        for (int t2 = 1; t2 < 4; ++t2)
          if (lrv[t2] < dm || (lrv[t2] == dm && lri[t2] < km)) { dm = lrv[t2]; km = lri[t2]; }
        lidx[rl] = km;
      }
      __syncthreads();
    }
  }
  __syncthreads();

  // ---- slim outputs: loss partial, quantized_st, single 1.0 per row ----
  // (zeros streamed in the chunk loop; barriers above drained them, so the 1.0
  //  stores below are safely ordered after)
  float lp = 0.f;
  for (int rl = w; rl < 128; rl += 4) {
    int row = row_base + rl;
    int idx = lidx[rl];
    // lane l covers the contiguous pair {2l, 2l+1}: 8B f32x2 loads (out+1 is only
    // 4B-aligned so stores stay scalar dword)
    f32x2 xv = *(const f32x2*)(X + row * DD + 2 * l);
    f32x2 ev = *(const f32x2*)(E + idx * DD + 2 * l);
    float d0 = ev[0] - xv[0], d1 = ev[1] - xv[1];
    __builtin_nontemporal_store(xv[0] + d0, out + 1 + row * DD + 2 * l);
    __builtin_nontemporal_store(xv[1] + d1, out + 1 + row * DD + 2 * l + 1);
    lp += d0 * d0 + d1 * d1;
    if (l == (idx & 63)) out[encb + row * KC + idx] = 1.f;              // the one-hot 1
  }
#pragma unroll
  for (int m = 1; m < 64; m <<= 1) lp += __shfl_xor(lp, m, 64);
  if (l == 0) lloss[w] = lp;
  __syncthreads();
  if (tid == 0) {
    float t = (lloss[0] + lloss[1] + lloss[2] + lloss[3]) *
              (1.25f / ((float)NROWS * (float)DD));
    atomicAdd(out, t);   // loss = q_latent + 0.25*e_latent = 1.25*mean
  }
}

extern "C" void kernel_launch(void* const* d_in, const int* in_sizes, int n_in,
                              void* d_out, int out_size, void* d_ws, size_t ws_size,
                              hipStream_t stream) {
  const float* X = (const float*)d_in[0];        // c_input [131072,128] fp32
  const float* E = (const float*)d_in[1];        // embedding [1024,128] fp32
  float* out = (float*)d_out;                    // [loss | quantized_st | encodings]
  short* EH = (short*)d_ws;                      // 256 KB bf16-hi fragments
  short* EL = EH + KC * DD;                      // 256 KB bf16-lo fragments
  float* SE = (float*)(EL + KC * DD);            // 4 KB row norms
  vq_prep<<<65, 256, 0, stream>>>(E, EH, EL, SE, out);
  vq_main<<<NROWS / 128, 256, 0, stream>>>(X, E, EH, EL, SE, out);
}